// Round 3
// baseline (826.050 us; speedup 1.0000x reference)
//
#include <hip/hip_runtime.h>
#include <hip/hip_bf16.h>

#define D 256
#define K 8192
#define NTOT 32768
#define BM 128
#define BN2 256
#define BD 32
#define CSPLIT 4
#define CT_PER (K / CSPLIT / BN2)  // 8 code-tiles per block

typedef __bf16 bf16x8 __attribute__((ext_vector_type(8)));
typedef float f32x4 __attribute__((ext_vector_type(4)));

__device__ __forceinline__ void gl_lds16(const void* g, void* l) {
    __builtin_amdgcn_global_load_lds(
        (__attribute__((address_space(1))) void*)(g),
        (__attribute__((address_space(3))) void*)(l), 16, 0, 0);
}

__device__ __forceinline__ unsigned int enc_f32(float f) {
    unsigned int u = __float_as_uint(f);
    return (u & 0x80000000u) ? ~u : (u | 0x80000000u);
}

__device__ __forceinline__ unsigned short f2bfu(float x) {
    __hip_bfloat16 h = __float2bfloat16(x);
    return __builtin_bit_cast(unsigned short, h);
}
__device__ __forceinline__ float bfu2f(unsigned short u) {
    return __bfloat162float(__builtin_bit_cast(__hip_bfloat16, u));
}

// ---------- z -> Fhi/Flo bf16 [NTOT, D] ----------
__global__ __launch_bounds__(256)
void conv_F(const float* __restrict__ z, unsigned short* __restrict__ Fhi,
            unsigned short* __restrict__ Flo) {
    int i4 = blockIdx.x * 256 + threadIdx.x;
    float4 v = ((const float4*)z)[i4];
    ushort4 h, l;
    h.x = f2bfu(v.x); l.x = f2bfu(v.x - bfu2f(h.x));
    h.y = f2bfu(v.y); l.y = f2bfu(v.y - bfu2f(h.y));
    h.z = f2bfu(v.z); l.z = f2bfu(v.z - bfu2f(h.z));
    h.w = f2bfu(v.w); l.w = f2bfu(v.w - bfu2f(h.w));
    ((ushort4*)Fhi)[i4] = h;
    ((ushort4*)Flo)[i4] = l;
}

// ---------- embed [D,K] -> EhiT/EloT bf16 [K,D] + ET fp32 [K,D] ----------
__global__ __launch_bounds__(256)
void conv_E(const float* __restrict__ E, unsigned short* __restrict__ EhiT,
            unsigned short* __restrict__ EloT, float* __restrict__ ET) {
    __shared__ float tile[64][65];
    int tid = threadIdx.x;
    int k0 = blockIdx.x * 64, d0 = blockIdx.y * 64;
#pragma unroll
    for (int it = 0; it < 16; ++it) {
        int idx = it * 256 + tid;
        int dr = idx >> 6, kc = idx & 63;
        tile[kc][dr] = E[(d0 + dr) * K + k0 + kc];
    }
    __syncthreads();
#pragma unroll
    for (int it = 0; it < 16; ++it) {
        int idx = it * 256 + tid;
        int kr = idx >> 6, dc = idx & 63;
        float v = tile[kr][dc];
        unsigned short h = f2bfu(v);
        int o = (k0 + kr) * D + d0 + dc;
        EhiT[o] = h;
        EloT[o] = f2bfu(v - bfu2f(h));
        ET[o] = v;
    }
}

// ---------- ||E_k||^2 ----------
__global__ __launch_bounds__(256)
void enorm_kernel(const float* __restrict__ ET, float* __restrict__ enorm) {
    int k = blockIdx.x * 256 + threadIdx.x;
    const float4* row = (const float4*)(ET + k * D);
    float s = 0.f;
#pragma unroll
    for (int d = 0; d < D / 4; ++d) {
        float4 v = row[d];
        s += v.x * v.x + v.y * v.y + v.z * v.z + v.w * v.w;
    }
    enorm[k] = s;
}

// ---------- MFMA dist + fused argmin ----------
// R0's proven 2-barrier single-buffer structure, widened to 8 waves / 128x256
// block tile (A re-read factor halves: fabric 4 GB -> 3 GB; barriers halve).
// acc init = -||E_k||^2/2 so the per-ct fold is a pure max (argmin dist ==
// argmax acc; dist recovered as -2*acc at the end).
__global__ __launch_bounds__(512, 4)
void mfma_dist_argmin(const unsigned short* __restrict__ Fhi,
                      const unsigned short* __restrict__ Flo,
                      const unsigned short* __restrict__ EhiT,
                      const unsigned short* __restrict__ EloT,
                      const float* __restrict__ enorm,
                      unsigned long long* __restrict__ bestpack) {
    __shared__ __align__(16) unsigned short Ah[BM * BD], Al[BM * BD];    // 8 KB each
    __shared__ __align__(16) unsigned short Bh[BN2 * BD], Bl[BN2 * BD];  // 16 KB each

    const int tid = threadIdx.x;   // 0..511
    const int wave = tid >> 6;     // 0..7
    const int lane = tid & 63;
    const int qd = lane >> 4;
    const int ln = lane & 15;
    const int wm = (wave >> 2) * 64;  // wave-rows: 0,64
    const int wn = (wave & 3) * 64;   // wave-cols: 0,64,128,192
    const int n0 = blockIdx.x * BM;
    const int c0 = blockIdx.y * (K / CSPLIT);

    // staging: thread t writes 16B at physical (row=t>>2, chunk=t&3);
    // global source chunk s_sw = (t&3) ^ rsw(row), rsw(row) = (row>>1)&3.
    // read: logical chunk qd of row lives at physical qd ^ ((ln>>1)&3).
    const int r_ = tid >> 2;          // 0..127
    const int s_sw = (tid & 3) ^ ((tid >> 3) & 3);
    const int csw = (qd ^ ((ln >> 1) & 3)) * 8;

    float bestv[16];
    int besti[16];
#pragma unroll
    for (int i = 0; i < 16; ++i) { bestv[i] = -3.402823466e38f; besti[i] = 0; }

    for (int ct = 0; ct < CT_PER; ++ct) {
        const int cb = c0 + ct * BN2;

        float en[4];
#pragma unroll
        for (int ni = 0; ni < 4; ++ni) en[ni] = enorm[cb + wn + ni * 16 + ln];

        f32x4 acc[4][4];
#pragma unroll
        for (int ni = 0; ni < 4; ++ni) {
            const float e = -0.5f * en[ni];
#pragma unroll
            for (int mi = 0; mi < 4; ++mi) acc[mi][ni] = (f32x4){e, e, e, e};
        }

        for (int d0 = 0; d0 < D; d0 += BD) {
            __syncthreads();  // previous step's readers done
            // A: 128 rows x 32 shorts in one pass (512 thr x 8 shorts)
            {
                const int ga = (n0 + r_) * D + d0 + s_sw * 8;
                gl_lds16(Fhi + ga, &Ah[wave * 512]);
                gl_lds16(Flo + ga, &Al[wave * 512]);
            }
            // B: 256 rows in two passes
#pragma unroll
            for (int it = 0; it < 2; ++it) {
                const int gb = (cb + it * 128 + r_) * D + d0 + s_sw * 8;
                const int lo = it * 4096 + wave * 512;
                gl_lds16(EhiT + gb, &Bh[lo]);
                gl_lds16(EloT + gb, &Bl[lo]);
            }
            __syncthreads();  // staging (incl. DMA drain) complete

            bf16x8 ah[4], al[4], bh[4], bl[4];
#pragma unroll
            for (int mi = 0; mi < 4; ++mi) {
                const int off = (wm + mi * 16 + ln) * BD + csw;
                ah[mi] = *(const bf16x8*)&Ah[off];
                al[mi] = *(const bf16x8*)&Al[off];
            }
#pragma unroll
            for (int ni = 0; ni < 4; ++ni) {
                const int off = (wn + ni * 16 + ln) * BD + csw;
                bh[ni] = *(const bf16x8*)&Bh[off];
                bl[ni] = *(const bf16x8*)&Bl[off];
            }

#pragma unroll
            for (int mi = 0; mi < 4; ++mi)
#pragma unroll
                for (int ni = 0; ni < 4; ++ni)
                    acc[mi][ni] = __builtin_amdgcn_mfma_f32_16x16x32_bf16(
                        ah[mi], bh[ni], acc[mi][ni], 0, 0, 0);
#pragma unroll
            for (int mi = 0; mi < 4; ++mi)
#pragma unroll
                for (int ni = 0; ni < 4; ++ni)
                    acc[mi][ni] = __builtin_amdgcn_mfma_f32_16x16x32_bf16(
                        ah[mi], bl[ni], acc[mi][ni], 0, 0, 0);
#pragma unroll
            for (int mi = 0; mi < 4; ++mi)
#pragma unroll
                for (int ni = 0; ni < 4; ++ni)
                    acc[mi][ni] = __builtin_amdgcn_mfma_f32_16x16x32_bf16(
                        al[mi], bh[ni], acc[mi][ni], 0, 0, 0);
        }

        // fold: pure argmax of acc (= dot - en/2) into per-row best
#pragma unroll
        for (int ni = 0; ni < 4; ++ni) {
            const int k = cb + wn + ni * 16 + ln;
#pragma unroll
            for (int mi = 0; mi < 4; ++mi) {
#pragma unroll
                for (int r = 0; r < 4; ++r) {
                    const float a = acc[mi][ni][r];
                    const int slot = mi * 4 + r;
                    if (a > bestv[slot]) { bestv[slot] = a; besti[slot] = k; }
                }
            }
        }
    }

    // cross-lane argmax per row (16 lanes of a qd-group share a row)
#pragma unroll
    for (int mi = 0; mi < 4; ++mi) {
#pragma unroll
        for (int r = 0; r < 4; ++r) {
            const int slot = mi * 4 + r;
            float v = bestv[slot];
            int ix = besti[slot];
#pragma unroll
            for (int off = 1; off < 16; off <<= 1) {
                float v2 = __shfl_xor(v, off);
                int i2 = __shfl_xor(ix, off);
                if (v2 > v || (v2 == v && i2 < ix)) { v = v2; ix = i2; }
            }
            if (ln == 0) {
                const int m = n0 + wm + mi * 16 + qd * 4 + r;
                const float dist = -2.0f * v;
                unsigned long long pack =
                    ((unsigned long long)enc_f32(dist) << 32) | (unsigned int)ix;
                atomicMin(&bestpack[m], pack);
            }
        }
    }
}

// ---------- gather quantize, diff partial, segment-sum scatter ----------
#define ROWS_PER_BLOCK 64
__global__ __launch_bounds__(256)
void assign_apply(const float* __restrict__ z,   // [NTOT, D]
                  const float* __restrict__ ET,  // [K, D]
                  const unsigned long long* __restrict__ bestpack,
                  float* __restrict__ out_q, float* __restrict__ out_ind,
                  float* __restrict__ out_diff,
                  float* __restrict__ counts, float* __restrict__ esumT) {
    const int tx = threadIdx.x;  // = d
    const int rbase = blockIdx.x * ROWS_PER_BLOCK;
    float part = 0.f;
    for (int r = 0; r < ROWS_PER_BLOCK; ++r) {
        int n = rbase + r;
        unsigned long long p = bestpack[n];
        int idx = (int)(p & 0xFFFFFFFFull);
        float f = z[n * D + tx];
        float q = ET[idx * D + tx];
        out_q[n * D + tx] = q;
        float dd = q - f;
        part += dd * dd;
        atomicAdd(&esumT[idx * D + tx], f);
        if (tx == 0) {
            atomicAdd(&counts[idx], 1.0f);
            out_ind[n] = (float)idx;
        }
    }
#pragma unroll
    for (int off = 32; off; off >>= 1) part += __shfl_down(part, off);
    __shared__ float wsum[4];
    if ((tx & 63) == 0) wsum[tx >> 6] = part;
    __syncthreads();
    if (tx == 0) {
        float t = wsum[0] + wsum[1] + wsum[2] + wsum[3];
        atomicAdd(out_diff, t * (0.25f / 8388608.0f));
    }
}

// ---------- cluster_size_new + total n ----------
__global__ __launch_bounds__(1024)
void csn_sum(const float* __restrict__ cs_in, const float* __restrict__ counts,
             float* __restrict__ csn, float* __restrict__ nsum) {
    const float decay = 0.99f;
    const float omd = 0.01f;
    int tx = threadIdx.x;
    float p = 0.f;
    for (int k = tx; k < K; k += 1024) {
        float v = decay * cs_in[k] + omd * counts[k];
        csn[k] = v;
        p += v;
    }
#pragma unroll
    for (int off = 32; off; off >>= 1) p += __shfl_down(p, off);
    __shared__ float red[16];
    if ((tx & 63) == 0) red[tx >> 6] = p;
    __syncthreads();
    if (tx == 0) {
        float t = 0.f;
        for (int i = 0; i < 16; ++i) t += red[i];
        nsum[0] = t;
    }
}

// ---------- embed_new = (decay*eavg + (1-decay)*esum) / cs ----------
__global__ __launch_bounds__(256)
void finalize(const float* __restrict__ eavg, const float* __restrict__ esumT,
              const float* __restrict__ csn, const float* __restrict__ nsum,
              float* __restrict__ out_enew) {
    const float decay = 0.99f;
    const float omd = 0.01f;
    const float keps = (float)(8192 * 1e-5);
    int idx = blockIdx.x * 256 + threadIdx.x;  // d*K + k
    float nv = nsum[0];
    int k = idx & (K - 1);
    int d = idx >> 13;
    float avg_new = decay * eavg[idx] + omd * esumT[k * D + d];
    float cs = (csn[k] + 1e-5f) / (nv + keps) * nv;
    out_enew[idx] = avg_new / cs;
}

extern "C" void kernel_launch(void* const* d_in, const int* in_sizes, int n_in,
                              void* d_out, int out_size, void* d_ws, size_t ws_size,
                              hipStream_t stream) {
    const float* z = (const float*)d_in[0];      // [32,32,32,256]
    const float* embed = (const float*)d_in[1];  // [256, 8192]
    const float* cs_in = (const float*)d_in[2];  // [8192]
    const float* eavg = (const float*)d_in[3];   // [256, 8192]

    float* out = (float*)d_out;
    float* out_q = out;                  // 8388608
    float* out_diff = out + 8388608;     // 1
    float* out_ind = out + 8388609;      // 32768
    float* out_enew = out + 8421377;     // 2097152

    char* ws = (char*)d_ws;
    unsigned long long* bestpack = (unsigned long long*)ws;      // 256 KB
    float* enorm = (float*)(ws + 262144);                        // 32 KB
    float* counts = (float*)(ws + 294912);                       // 32 KB
    float* csn = (float*)(ws + 327680);                          // 32 KB
    float* nsum = (float*)(ws + 360448);                         // pad
    float* esumT = (float*)(ws + 360704);                        // 8 MB [K,D]
    unsigned short* Fhi = (unsigned short*)(ws + 8749312);       // 16 MB
    unsigned short* Flo = (unsigned short*)(ws + 25526528);      // 16 MB
    unsigned short* EhiT = (unsigned short*)(ws + 42303744);     // 4 MB
    unsigned short* EloT = (unsigned short*)(ws + 46498048);     // 4 MB
    float* ET = (float*)(ws + 50692352);                         // 8 MB

    hipMemsetAsync(bestpack, 0xFF, NTOT * 8, stream);
    hipMemsetAsync(counts, 0, K * 4, stream);
    hipMemsetAsync(esumT, 0, K * D * 4, stream);
    hipMemsetAsync(out_diff, 0, 4, stream);

    conv_F<<<NTOT * D / 4 / 256, 256, 0, stream>>>(z, Fhi, Flo);
    conv_E<<<dim3(K / 64, D / 64), 256, 0, stream>>>(embed, EhiT, EloT, ET);
    enorm_kernel<<<K / 256, 256, 0, stream>>>(ET, enorm);
    mfma_dist_argmin<<<dim3(NTOT / BM, CSPLIT), 512, 0, stream>>>(Fhi, Flo, EhiT, EloT,
                                                                  enorm, bestpack);
    assign_apply<<<NTOT / ROWS_PER_BLOCK, 256, 0, stream>>>(z, ET, bestpack, out_q,
                                                            out_ind, out_diff, counts, esumT);
    csn_sum<<<1, 1024, 0, stream>>>(cs_in, counts, csn, nsum);
    finalize<<<(D * K) / 256, 256, 0, stream>>>(eavg, esumT, csn, nsum, out_enew);
}

// Round 4
// 706.998 us; speedup vs baseline: 1.1684x; 1.1684x over previous
//
#include <hip/hip_runtime.h>
#include <hip/hip_bf16.h>

#define D 256
#define K 8192
#define NTOT 32768
#define BM 128
#define BN2 128
#define BD 32
#define CSPLIT 4
#define CT_PER (K / CSPLIT / BN2)  // 16 code-tiles per block

typedef __bf16 bf16x8 __attribute__((ext_vector_type(8)));
typedef float f32x4 __attribute__((ext_vector_type(4)));

__device__ __forceinline__ void gl_lds16(const void* g, void* l) {
    __builtin_amdgcn_global_load_lds(
        (__attribute__((address_space(1))) void*)(g),
        (__attribute__((address_space(3))) void*)(l), 16, 0, 0);
}

__device__ __forceinline__ unsigned int enc_f32(float f) {
    unsigned int u = __float_as_uint(f);
    return (u & 0x80000000u) ? ~u : (u | 0x80000000u);
}

__device__ __forceinline__ unsigned short f2bfu(float x) {
    __hip_bfloat16 h = __float2bfloat16(x);
    return __builtin_bit_cast(unsigned short, h);
}
__device__ __forceinline__ float bfu2f(unsigned short u) {
    return __bfloat162float(__builtin_bit_cast(__hip_bfloat16, u));
}

// ---------- fused prep: conv_F (blocks 0..8191) + conv_E/enorm/S0 (8192..8703) ----------
__global__ __launch_bounds__(256)
void prep(const float* __restrict__ z, const float* __restrict__ E,
          const float* __restrict__ cs_in,
          unsigned short* __restrict__ Fhi, unsigned short* __restrict__ Flo,
          unsigned short* __restrict__ EhiT, unsigned short* __restrict__ EloT,
          float* __restrict__ ET, float* __restrict__ enorm,
          float* __restrict__ nsum) {
    __shared__ float tile[64][65];
    const int tid = threadIdx.x;
    const int bid = blockIdx.x;

    if (bid < 8192) {
        // conv_F: z -> Fhi/Flo bf16 [NTOT, D]
        int i4 = bid * 256 + tid;
        float4 v = ((const float4*)z)[i4];
        ushort4 h, l;
        h.x = f2bfu(v.x); l.x = f2bfu(v.x - bfu2f(h.x));
        h.y = f2bfu(v.y); l.y = f2bfu(v.y - bfu2f(h.y));
        h.z = f2bfu(v.z); l.z = f2bfu(v.z - bfu2f(h.z));
        h.w = f2bfu(v.w); l.w = f2bfu(v.w - bfu2f(h.w));
        ((ushort4*)Fhi)[i4] = h;
        ((ushort4*)Flo)[i4] = l;
        return;
    }

    // conv_E part: embed [D,K] -> EhiT/EloT [K,D] + ET fp32 [K,D] + enorm + S0
    const int eb = bid - 8192;           // 0..511
    const int k0 = (eb & 127) * 64;      // K/64 = 128 k-blocks
    const int d0 = (eb >> 7) * 64;       // 4 d-blocks

    // S0 = sum(cs_in): one wave per k-block (d-block 0 only), 1 atomic/block
    if (eb < 128 && tid < 64) {
        float s = cs_in[k0 + tid];
#pragma unroll
        for (int off = 32; off; off >>= 1) s += __shfl_down(s, off);
        if (tid == 0) atomicAdd(nsum, s);
    }

#pragma unroll
    for (int it = 0; it < 16; ++it) {
        int idx = it * 256 + tid;
        int dr = idx >> 6, kc = idx & 63;
        tile[kc][dr] = E[(d0 + dr) * K + k0 + kc];
    }
    __syncthreads();
#pragma unroll
    for (int it = 0; it < 16; ++it) {
        int idx = it * 256 + tid;
        int kr = idx >> 6, dc = idx & 63;  // kr = it*4 + (tid>>6): uniform per wave
        float v = tile[kr][dc];
        unsigned short h = f2bfu(v);
        int o = (k0 + kr) * D + d0 + dc;
        EhiT[o] = h;
        EloT[o] = f2bfu(v - bfu2f(h));
        ET[o] = v;
        // enorm partial: wave's 64 lanes hold row kr's 64 d-values of this d-block
        float ss = v * v;
#pragma unroll
        for (int off = 32; off; off >>= 1) ss += __shfl_down(ss, off);
        if ((tid & 63) == 0) atomicAdd(&enorm[k0 + it * 4 + (tid >> 6)], ss);
    }
}

// ---------- MFMA dist + fused argmin (EXACT R0 structure: 437 us proven) ----------
__global__ __launch_bounds__(256)
void mfma_dist_argmin(const unsigned short* __restrict__ Fhi,
                      const unsigned short* __restrict__ Flo,
                      const unsigned short* __restrict__ EhiT,
                      const unsigned short* __restrict__ EloT,
                      const float* __restrict__ enorm,
                      unsigned long long* __restrict__ bestpack) {
    __shared__ unsigned short Ah[BM * BD], Al[BM * BD], Bh[BN2 * BD], Bl[BN2 * BD];

    const int tid = threadIdx.x;
    const int wave = tid >> 6;
    const int lane = tid & 63;
    const int qd = lane >> 4;
    const int ln = lane & 15;
    const int wm = (wave >> 1) * 64;
    const int wn = (wave & 1) * 64;
    const int n0 = blockIdx.x * BM;
    const int c0 = blockIdx.y * (K / CSPLIT);
    // staging: lane tid -> physical (row tid>>2, chunk tid&3); swizzled global chunk
    const int r_ = tid >> 2;
    const int s_sw = (tid & 3) ^ ((tid >> 3) & 3);
    // read swizzle: logical chunk qd of row ln lives at physical chunk qd^((ln>>1)&3)
    const int csw = (qd ^ ((ln >> 1) & 3)) * 8;

    float bestv[16];
    int besti[16];
#pragma unroll
    for (int i = 0; i < 16; ++i) { bestv[i] = 3.402823466e38f; besti[i] = 0; }

    for (int ct = 0; ct < CT_PER; ++ct) {
        const int cb = c0 + ct * BN2;
        f32x4 acc[4][4];
#pragma unroll
        for (int mi = 0; mi < 4; ++mi)
#pragma unroll
            for (int ni = 0; ni < 4; ++ni) acc[mi][ni] = (f32x4){0.f, 0.f, 0.f, 0.f};

        for (int d0 = 0; d0 < D; d0 += BD) {
            __syncthreads();
#pragma unroll
            for (int it = 0; it < 2; ++it) {
                const int ga = (n0 + it * 64 + r_) * D + d0 + s_sw * 8;
                const int gb = (cb + it * 64 + r_) * D + d0 + s_sw * 8;
                const int lo = it * 2048 + wave * 512;
                gl_lds16(Fhi + ga, &Ah[lo]);
                gl_lds16(Flo + ga, &Al[lo]);
                gl_lds16(EhiT + gb, &Bh[lo]);
                gl_lds16(EloT + gb, &Bl[lo]);
            }
            __syncthreads();

            bf16x8 ah[4], al[4], bh[4], bl[4];
#pragma unroll
            for (int mi = 0; mi < 4; ++mi) {
                int off = (wm + mi * 16 + ln) * BD + csw;
                ah[mi] = *(const bf16x8*)&Ah[off];
                al[mi] = *(const bf16x8*)&Al[off];
            }
#pragma unroll
            for (int ni = 0; ni < 4; ++ni) {
                int off = (wn + ni * 16 + ln) * BD + csw;
                bh[ni] = *(const bf16x8*)&Bh[off];
                bl[ni] = *(const bf16x8*)&Bl[off];
            }
#pragma unroll
            for (int mi = 0; mi < 4; ++mi)
#pragma unroll
                for (int ni = 0; ni < 4; ++ni)
                    acc[mi][ni] = __builtin_amdgcn_mfma_f32_16x16x32_bf16(
                        ah[mi], bh[ni], acc[mi][ni], 0, 0, 0);
#pragma unroll
            for (int mi = 0; mi < 4; ++mi)
#pragma unroll
                for (int ni = 0; ni < 4; ++ni)
                    acc[mi][ni] = __builtin_amdgcn_mfma_f32_16x16x32_bf16(
                        ah[mi], bl[ni], acc[mi][ni], 0, 0, 0);
#pragma unroll
            for (int mi = 0; mi < 4; ++mi)
#pragma unroll
                for (int ni = 0; ni < 4; ++ni)
                    acc[mi][ni] = __builtin_amdgcn_mfma_f32_16x16x32_bf16(
                        al[mi], bh[ni], acc[mi][ni], 0, 0, 0);
        }

        float en[4];
#pragma unroll
        for (int ni = 0; ni < 4; ++ni) en[ni] = enorm[cb + wn + ni * 16 + ln];
#pragma unroll
        for (int ni = 0; ni < 4; ++ni) {
            int k = cb + wn + ni * 16 + ln;
#pragma unroll
            for (int mi = 0; mi < 4; ++mi) {
                f32x4 a = acc[mi][ni];
#pragma unroll
                for (int r = 0; r < 4; ++r) {
                    float dist = en[ni] - 2.0f * a[r];
                    int bi = mi * 4 + r;
                    if (dist < bestv[bi]) { bestv[bi] = dist; besti[bi] = k; }
                }
            }
        }
    }

#pragma unroll
    for (int mi = 0; mi < 4; ++mi) {
#pragma unroll
        for (int r = 0; r < 4; ++r) {
            int bi = mi * 4 + r;
            float v = bestv[bi];
            int ix = besti[bi];
#pragma unroll
            for (int off = 1; off < 16; off <<= 1) {
                float v2 = __shfl_xor(v, off);
                int i2 = __shfl_xor(ix, off);
                if (v2 < v || (v2 == v && i2 < ix)) { v = v2; ix = i2; }
            }
            if (ln == 0) {
                int m = n0 + wm + mi * 16 + qd * 4 + r;
                unsigned long long pack =
                    ((unsigned long long)enc_f32(v) << 32) | (unsigned int)ix;
                atomicMin(&bestpack[m], pack);
            }
        }
    }
}

// ---------- gather quantize, diff partial, segment-sum scatter (float4) ----------
#define ROWS_PER_BLOCK 64
__global__ __launch_bounds__(256)
void assign_apply(const float* __restrict__ z,   // [NTOT, D]
                  const float* __restrict__ ET,  // [K, D]
                  const unsigned long long* __restrict__ bestpack,
                  float* __restrict__ out_q, float* __restrict__ out_ind,
                  float* __restrict__ counts, float* __restrict__ esumT,
                  float* __restrict__ diffpart) {
    const int tx = threadIdx.x;
    const int l = tx & 63;    // float4 index within row (64 x 4 = 256 floats)
    const int sub = tx >> 6;  // 4 rows in flight
    const int rbase = blockIdx.x * ROWS_PER_BLOCK;
    const float4* z4 = (const float4*)z;
    const float4* ET4 = (const float4*)ET;
    float4* q4 = (float4*)out_q;
    float part = 0.f;
    for (int r = sub; r < ROWS_PER_BLOCK; r += 4) {
        const int n = rbase + r;
        const unsigned long long p = bestpack[n];
        const int idx = (int)(p & 0xFFFFFFFFull);
        float4 f = z4[n * 64 + l];
        float4 q = ET4[idx * 64 + l];
        q4[n * 64 + l] = q;
        float dx = q.x - f.x, dy = q.y - f.y, dz = q.z - f.z, dw = q.w - f.w;
        part += dx * dx + dy * dy + dz * dz + dw * dw;
        float* ep = esumT + idx * D + l * 4;
        atomicAdd(ep + 0, f.x);
        atomicAdd(ep + 1, f.y);
        atomicAdd(ep + 2, f.z);
        atomicAdd(ep + 3, f.w);
        if (l == 0) {
            atomicAdd(&counts[idx], 1.0f);
            out_ind[n] = (float)idx;
        }
    }
#pragma unroll
    for (int off = 32; off; off >>= 1) part += __shfl_down(part, off);
    __shared__ float wsum[4];
    if ((tx & 63) == 0) wsum[tx >> 6] = part;
    __syncthreads();
    if (tx == 0) diffpart[blockIdx.x] = wsum[0] + wsum[1] + wsum[2] + wsum[3];
}

// ---------- embed_new (csn/nsum fused) + diff final reduce ----------
__global__ __launch_bounds__(256)
void finalize(const float* __restrict__ eavg, const float* __restrict__ esumT,
              const float* __restrict__ cs_in, const float* __restrict__ counts,
              const float* __restrict__ nsum, const float* __restrict__ diffpart,
              float* __restrict__ out_enew, float* __restrict__ out_diff) {
    const int tid = threadIdx.x;
    if (blockIdx.x == 0) {
        float p = diffpart[tid] + diffpart[tid + 256];
#pragma unroll
        for (int off = 32; off; off >>= 1) p += __shfl_down(p, off);
        __shared__ float sred[4];
        if ((tid & 63) == 0) sred[tid >> 6] = p;
        __syncthreads();
        if (tid == 0)
            *out_diff = (sred[0] + sred[1] + sred[2] + sred[3]) * (0.25f / 8388608.0f);
    }
    const int idx = blockIdx.x * 256 + tid;  // d*K + k
    const float nv = 0.99f * nsum[0] + 0.01f * 32768.0f;  // sum(counts) == NTOT exactly
    const int k = idx & (K - 1);
    const int d = idx >> 13;
    const float csn_k = 0.99f * cs_in[k] + 0.01f * counts[k];
    const float avg_new = 0.99f * eavg[idx] + 0.01f * esumT[k * D + d];
    const float cs = (csn_k + 1e-5f) / (nv + 0.08192f) * nv;
    out_enew[idx] = avg_new / cs;
}

extern "C" void kernel_launch(void* const* d_in, const int* in_sizes, int n_in,
                              void* d_out, int out_size, void* d_ws, size_t ws_size,
                              hipStream_t stream) {
    const float* z = (const float*)d_in[0];      // [32,32,32,256]
    const float* embed = (const float*)d_in[1];  // [256, 8192]
    const float* cs_in = (const float*)d_in[2];  // [8192]
    const float* eavg = (const float*)d_in[3];   // [256, 8192]

    float* out = (float*)d_out;
    float* out_q = out;                  // 8388608
    float* out_diff = out + 8388608;     // 1
    float* out_ind = out + 8388609;      // 32768
    float* out_enew = out + 8421377;     // 2097152

    char* ws = (char*)d_ws;
    unsigned long long* bestpack = (unsigned long long*)ws;   // 256 KB (0xFF)
    float* enorm = (float*)(ws + 262144);                     // 32 KB  (zero)
    float* counts = (float*)(ws + 294912);                    // 32 KB  (zero)
    float* nsum = (float*)(ws + 327680);                      // 4 B    (zero)
    float* diffpart = (float*)(ws + 329728);                  // 2 KB   (no init needed)
    float* esumT = (float*)(ws + 331776);                     // 8 MB   (zero) [K,D]
    unsigned short* Fhi = (unsigned short*)(ws + 8720384);    // 16 MB
    unsigned short* Flo = (unsigned short*)(ws + 25497600);   // 16 MB
    unsigned short* EhiT = (unsigned short*)(ws + 42274816);  // 4 MB
    unsigned short* EloT = (unsigned short*)(ws + 46469120);  // 4 MB
    float* ET = (float*)(ws + 50663424);                      // 8 MB

    hipMemsetAsync(bestpack, 0xFF, 262144, stream);
    // one contiguous zero region: enorm+counts+nsum+diffpart+esumT
    hipMemsetAsync(ws + 262144, 0, 331776 - 262144 + 8388608, stream);

    prep<<<8192 + 512, 256, 0, stream>>>(z, embed, cs_in, Fhi, Flo, EhiT, EloT, ET,
                                         enorm, nsum);
    mfma_dist_argmin<<<dim3(NTOT / BM, CSPLIT), 256, 0, stream>>>(Fhi, Flo, EhiT, EloT,
                                                                  enorm, bestpack);
    assign_apply<<<NTOT / ROWS_PER_BLOCK, 256, 0, stream>>>(z, ET, bestpack, out_q,
                                                            out_ind, counts, esumT,
                                                            diffpart);
    finalize<<<(D * K) / 256, 256, 0, stream>>>(eavg, esumT, cs_in, counts, nsum,
                                                diffpart, out_enew, out_diff);
}

// Round 5
// 592.129 us; speedup vs baseline: 1.3950x; 1.1940x over previous
//
#include <hip/hip_runtime.h>
#include <hip/hip_bf16.h>

#define D 256
#define K 8192
#define NTOT 32768
#define BM 128
#define BN2 128
#define BD 32
#define CSPLIT 4
#define CT_PER (K / CSPLIT / BN2)  // 16 code-tiles per block

typedef __bf16 bf16x8 __attribute__((ext_vector_type(8)));
typedef float f32x4 __attribute__((ext_vector_type(4)));

__device__ __forceinline__ void gl_lds16(const void* g, void* l) {
    __builtin_amdgcn_global_load_lds(
        (__attribute__((address_space(1))) void*)(g),
        (__attribute__((address_space(3))) void*)(l), 16, 0, 0);
}

__device__ __forceinline__ unsigned int enc_f32(float f) {
    unsigned int u = __float_as_uint(f);
    return (u & 0x80000000u) ? ~u : (u | 0x80000000u);
}

__device__ __forceinline__ unsigned short f2bfu(float x) {
    __hip_bfloat16 h = __float2bfloat16(x);
    return __builtin_bit_cast(unsigned short, h);
}
__device__ __forceinline__ float bfu2f(unsigned short u) {
    return __bfloat162float(__builtin_bit_cast(__hip_bfloat16, u));
}

// ---------- z -> Fhi/Flo bf16 [NTOT, D] ----------
__global__ __launch_bounds__(256)
void conv_F(const float* __restrict__ z, unsigned short* __restrict__ Fhi,
            unsigned short* __restrict__ Flo) {
    int i4 = blockIdx.x * 256 + threadIdx.x;
    float4 v = ((const float4*)z)[i4];
    ushort4 h, l;
    h.x = f2bfu(v.x); l.x = f2bfu(v.x - bfu2f(h.x));
    h.y = f2bfu(v.y); l.y = f2bfu(v.y - bfu2f(h.y));
    h.z = f2bfu(v.z); l.z = f2bfu(v.z - bfu2f(h.z));
    h.w = f2bfu(v.w); l.w = f2bfu(v.w - bfu2f(h.w));
    ((ushort4*)Fhi)[i4] = h;
    ((ushort4*)Flo)[i4] = l;
}

// ---------- embed [D,K] -> EhiT/EloT bf16 [K,D] + ET fp32 [K,D] + sum(cs_in) ----------
__global__ __launch_bounds__(256)
void conv_E(const float* __restrict__ E, const float* __restrict__ cs_in,
            unsigned short* __restrict__ EhiT, unsigned short* __restrict__ EloT,
            float* __restrict__ ET, float* __restrict__ nsum) {
    __shared__ float tile[64][65];
    int tid = threadIdx.x;
    int k0 = blockIdx.x * 64, d0 = blockIdx.y * 64;

    // sum(cs_in) partial: 128 k-blocks (y==0), one wave, one atomic each
    if (blockIdx.y == 0 && tid < 64) {
        float s = cs_in[k0 + tid];
#pragma unroll
        for (int off = 32; off; off >>= 1) s += __shfl_down(s, off);
        if (tid == 0) atomicAdd(nsum, s);
    }

#pragma unroll
    for (int it = 0; it < 16; ++it) {
        int idx = it * 256 + tid;
        int dr = idx >> 6, kc = idx & 63;
        tile[kc][dr] = E[(d0 + dr) * K + k0 + kc];
    }
    __syncthreads();
#pragma unroll
    for (int it = 0; it < 16; ++it) {
        int idx = it * 256 + tid;
        int kr = idx >> 6, dc = idx & 63;
        float v = tile[kr][dc];
        unsigned short h = f2bfu(v);
        int o = (k0 + kr) * D + d0 + dc;
        EhiT[o] = h;
        EloT[o] = f2bfu(v - bfu2f(h));
        ET[o] = v;
    }
}

// ---------- ||E_k||^2 ----------
__global__ __launch_bounds__(256)
void enorm_kernel(const float* __restrict__ ET, float* __restrict__ enorm) {
    int k = blockIdx.x * 256 + threadIdx.x;
    const float4* row = (const float4*)(ET + k * D);
    float s = 0.f;
#pragma unroll
    for (int d = 0; d < D / 4; ++d) {
        float4 v = row[d];
        s += v.x * v.x + v.y * v.y + v.z * v.z + v.w * v.w;
    }
    enorm[k] = s;
}

// ---------- MFMA dist + fused argmin (EXACT R0 structure: 437 us proven) ----------
__global__ __launch_bounds__(256)
void mfma_dist_argmin(const unsigned short* __restrict__ Fhi,
                      const unsigned short* __restrict__ Flo,
                      const unsigned short* __restrict__ EhiT,
                      const unsigned short* __restrict__ EloT,
                      const float* __restrict__ enorm,
                      unsigned long long* __restrict__ bestpack) {
    __shared__ unsigned short Ah[BM * BD], Al[BM * BD], Bh[BN2 * BD], Bl[BN2 * BD];

    const int tid = threadIdx.x;
    const int wave = tid >> 6;
    const int lane = tid & 63;
    const int qd = lane >> 4;
    const int ln = lane & 15;
    const int wm = (wave >> 1) * 64;
    const int wn = (wave & 1) * 64;
    const int n0 = blockIdx.x * BM;
    const int c0 = blockIdx.y * (K / CSPLIT);
    // staging: lane tid -> physical (row tid>>2, chunk tid&3); swizzled global chunk
    const int r_ = tid >> 2;
    const int s_sw = (tid & 3) ^ ((tid >> 3) & 3);
    // read swizzle: logical chunk qd of row ln lives at physical chunk qd^((ln>>1)&3)
    const int csw = (qd ^ ((ln >> 1) & 3)) * 8;

    float bestv[16];
    int besti[16];
#pragma unroll
    for (int i = 0; i < 16; ++i) { bestv[i] = 3.402823466e38f; besti[i] = 0; }

    for (int ct = 0; ct < CT_PER; ++ct) {
        const int cb = c0 + ct * BN2;
        f32x4 acc[4][4];
#pragma unroll
        for (int mi = 0; mi < 4; ++mi)
#pragma unroll
            for (int ni = 0; ni < 4; ++ni) acc[mi][ni] = (f32x4){0.f, 0.f, 0.f, 0.f};

        for (int d0 = 0; d0 < D; d0 += BD) {
            __syncthreads();
#pragma unroll
            for (int it = 0; it < 2; ++it) {
                const int ga = (n0 + it * 64 + r_) * D + d0 + s_sw * 8;
                const int gb = (cb + it * 64 + r_) * D + d0 + s_sw * 8;
                const int lo = it * 2048 + wave * 512;
                gl_lds16(Fhi + ga, &Ah[lo]);
                gl_lds16(Flo + ga, &Al[lo]);
                gl_lds16(EhiT + gb, &Bh[lo]);
                gl_lds16(EloT + gb, &Bl[lo]);
            }
            __syncthreads();

            bf16x8 ah[4], al[4], bh[4], bl[4];
#pragma unroll
            for (int mi = 0; mi < 4; ++mi) {
                int off = (wm + mi * 16 + ln) * BD + csw;
                ah[mi] = *(const bf16x8*)&Ah[off];
                al[mi] = *(const bf16x8*)&Al[off];
            }
#pragma unroll
            for (int ni = 0; ni < 4; ++ni) {
                int off = (wn + ni * 16 + ln) * BD + csw;
                bh[ni] = *(const bf16x8*)&Bh[off];
                bl[ni] = *(const bf16x8*)&Bl[off];
            }
#pragma unroll
            for (int mi = 0; mi < 4; ++mi)
#pragma unroll
                for (int ni = 0; ni < 4; ++ni)
                    acc[mi][ni] = __builtin_amdgcn_mfma_f32_16x16x32_bf16(
                        ah[mi], bh[ni], acc[mi][ni], 0, 0, 0);
#pragma unroll
            for (int mi = 0; mi < 4; ++mi)
#pragma unroll
                for (int ni = 0; ni < 4; ++ni)
                    acc[mi][ni] = __builtin_amdgcn_mfma_f32_16x16x32_bf16(
                        ah[mi], bl[ni], acc[mi][ni], 0, 0, 0);
#pragma unroll
            for (int mi = 0; mi < 4; ++mi)
#pragma unroll
                for (int ni = 0; ni < 4; ++ni)
                    acc[mi][ni] = __builtin_amdgcn_mfma_f32_16x16x32_bf16(
                        al[mi], bh[ni], acc[mi][ni], 0, 0, 0);
        }

        float en[4];
#pragma unroll
        for (int ni = 0; ni < 4; ++ni) en[ni] = enorm[cb + wn + ni * 16 + ln];
#pragma unroll
        for (int ni = 0; ni < 4; ++ni) {
            int k = cb + wn + ni * 16 + ln;
#pragma unroll
            for (int mi = 0; mi < 4; ++mi) {
                f32x4 a = acc[mi][ni];
#pragma unroll
                for (int r = 0; r < 4; ++r) {
                    float dist = en[ni] - 2.0f * a[r];
                    int bi = mi * 4 + r;
                    if (dist < bestv[bi]) { bestv[bi] = dist; besti[bi] = k; }
                }
            }
        }
    }

#pragma unroll
    for (int mi = 0; mi < 4; ++mi) {
#pragma unroll
        for (int r = 0; r < 4; ++r) {
            int bi = mi * 4 + r;
            float v = bestv[bi];
            int ix = besti[bi];
#pragma unroll
            for (int off = 1; off < 16; off <<= 1) {
                float v2 = __shfl_xor(v, off);
                int i2 = __shfl_xor(ix, off);
                if (v2 < v || (v2 == v && i2 < ix)) { v = v2; ix = i2; }
            }
            if (ln == 0) {
                int m = n0 + wm + mi * 16 + qd * 4 + r;
                unsigned long long pack =
                    ((unsigned long long)enc_f32(v) << 32) | (unsigned int)ix;
                atomicMin(&bestpack[m], pack);
            }
        }
    }
}

// ---------- gather quantize, diff partial, segment-sum scatter ----------
// R0 body exactly; ROWS_PER_BLOCK 64->16 (2048 blocks: 4x TLP for the
// dependent bestpack->ET gather chain; atomics stay stride-4B per-thread).
#define ROWS_PER_BLOCK 16
__global__ __launch_bounds__(256)
void assign_apply(const float* __restrict__ z,   // [NTOT, D]
                  const float* __restrict__ ET,  // [K, D]
                  const unsigned long long* __restrict__ bestpack,
                  float* __restrict__ out_q, float* __restrict__ out_ind,
                  float* __restrict__ out_diff,
                  float* __restrict__ counts, float* __restrict__ esumT) {
    const int tx = threadIdx.x;  // = d
    const int rbase = blockIdx.x * ROWS_PER_BLOCK;
    float part = 0.f;
    for (int r = 0; r < ROWS_PER_BLOCK; ++r) {
        int n = rbase + r;
        unsigned long long p = bestpack[n];
        int idx = (int)(p & 0xFFFFFFFFull);
        float f = z[n * D + tx];
        float q = ET[idx * D + tx];
        out_q[n * D + tx] = q;
        float dd = q - f;
        part += dd * dd;
        atomicAdd(&esumT[idx * D + tx], f);
        if (tx == 0) {
            atomicAdd(&counts[idx], 1.0f);
            out_ind[n] = (float)idx;
        }
    }
#pragma unroll
    for (int off = 32; off; off >>= 1) part += __shfl_down(part, off);
    __shared__ float wsum[4];
    if ((tx & 63) == 0) wsum[tx >> 6] = part;
    __syncthreads();
    if (tx == 0) {
        float t = wsum[0] + wsum[1] + wsum[2] + wsum[3];
        atomicAdd(out_diff, t * (0.25f / 8388608.0f));
    }
}

// ---------- embed_new, csn/nsum fused (csn_sum kernel eliminated) ----------
__global__ __launch_bounds__(256)
void finalize(const float* __restrict__ eavg, const float* __restrict__ esumT,
              const float* __restrict__ cs_in, const float* __restrict__ counts,
              const float* __restrict__ nsum, float* __restrict__ out_enew) {
    const int idx = blockIdx.x * 256 + threadIdx.x;  // d*K + k
    // n = sum(csn) = 0.99*sum(cs_in) + 0.01*sum(counts); sum(counts) == NTOT exact
    const float nv = 0.99f * nsum[0] + 0.01f * 32768.0f;
    const int k = idx & (K - 1);
    const int d = idx >> 13;
    const float csn_k = 0.99f * cs_in[k] + 0.01f * counts[k];
    const float avg_new = 0.99f * eavg[idx] + 0.01f * esumT[k * D + d];
    const float cs = (csn_k + 1e-5f) / (nv + 0.08192f) * nv;
    out_enew[idx] = avg_new / cs;
}

extern "C" void kernel_launch(void* const* d_in, const int* in_sizes, int n_in,
                              void* d_out, int out_size, void* d_ws, size_t ws_size,
                              hipStream_t stream) {
    const float* z = (const float*)d_in[0];      // [32,32,32,256]
    const float* embed = (const float*)d_in[1];  // [256, 8192]
    const float* cs_in = (const float*)d_in[2];  // [8192]
    const float* eavg = (const float*)d_in[3];   // [256, 8192]

    float* out = (float*)d_out;
    float* out_q = out;                  // 8388608
    float* out_diff = out + 8388608;     // 1
    float* out_ind = out + 8388609;      // 32768
    float* out_enew = out + 8421377;     // 2097152

    char* ws = (char*)d_ws;
    unsigned long long* bestpack = (unsigned long long*)ws;   // 256 KB (0xFF)
    float* counts = (float*)(ws + 262144);                    // 32 KB (zero)
    float* nsum = (float*)(ws + 294912);                      // 256 B (zero)
    float* esumT = (float*)(ws + 295168);                     // 8 MB  (zero) [K,D]
    float* enorm = (float*)(ws + 8683776);                    // 32 KB (written, no init)
    unsigned short* Fhi = (unsigned short*)(ws + 8716544);    // 16 MB
    unsigned short* Flo = (unsigned short*)(ws + 25493760);   // 16 MB
    unsigned short* EhiT = (unsigned short*)(ws + 42270976);  // 4 MB
    unsigned short* EloT = (unsigned short*)(ws + 46465280);  // 4 MB
    float* ET = (float*)(ws + 50659584);                      // 8 MB

    hipMemsetAsync(bestpack, 0xFF, 262144, stream);
    hipMemsetAsync(ws + 262144, 0, 8421632, stream);  // counts+nsum+esumT
    hipMemsetAsync(out_diff, 0, 4, stream);

    conv_F<<<NTOT * D / 4 / 256, 256, 0, stream>>>(z, Fhi, Flo);
    conv_E<<<dim3(K / 64, D / 64), 256, 0, stream>>>(embed, cs_in, EhiT, EloT, ET, nsum);
    enorm_kernel<<<K / 256, 256, 0, stream>>>(ET, enorm);
    mfma_dist_argmin<<<dim3(NTOT / BM, CSPLIT), 256, 0, stream>>>(Fhi, Flo, EhiT, EloT,
                                                                  enorm, bestpack);
    assign_apply<<<NTOT / ROWS_PER_BLOCK, 256, 0, stream>>>(z, ET, bestpack, out_q,
                                                            out_ind, out_diff, counts,
                                                            esumT);
    finalize<<<(D * K) / 256, 256, 0, stream>>>(eavg, esumT, cs_in, counts, nsum,
                                                out_enew);
}

// Round 7
// 591.094 us; speedup vs baseline: 1.3975x; 1.0018x over previous
//
#include <hip/hip_runtime.h>
#include <hip/hip_bf16.h>

#define D 256
#define K 8192
#define NTOT 32768
#define BM 128
#define BN2 128
#define BD 32
#define CSPLIT 4
#define CT_PER (K / CSPLIT / BN2)  // 16 code-tiles per block

typedef __bf16 bf16x8 __attribute__((ext_vector_type(8)));
typedef float f32x4 __attribute__((ext_vector_type(4)));

__device__ __forceinline__ void gl_lds16(const void* g, void* l) {
    __builtin_amdgcn_global_load_lds(
        (__attribute__((address_space(1))) void*)(g),
        (__attribute__((address_space(3))) void*)(l), 16, 0, 0);
}

__device__ __forceinline__ unsigned int enc_f32(float f) {
    unsigned int u = __float_as_uint(f);
    return (u & 0x80000000u) ? ~u : (u | 0x80000000u);
}

__device__ __forceinline__ unsigned short f2bfu(float x) {
    __hip_bfloat16 h = __float2bfloat16(x);
    return __builtin_bit_cast(unsigned short, h);
}
__device__ __forceinline__ float bfu2f(unsigned short u) {
    return __bfloat162float(__builtin_bit_cast(__hip_bfloat16, u));
}

// ---------- z -> Fhi/Flo bf16 [NTOT, D] ----------
__global__ __launch_bounds__(256)
void conv_F(const float* __restrict__ z, unsigned short* __restrict__ Fhi,
            unsigned short* __restrict__ Flo) {
    int i4 = blockIdx.x * 256 + threadIdx.x;
    float4 v = ((const float4*)z)[i4];
    ushort4 h, l;
    h.x = f2bfu(v.x); l.x = f2bfu(v.x - bfu2f(h.x));
    h.y = f2bfu(v.y); l.y = f2bfu(v.y - bfu2f(h.y));
    h.z = f2bfu(v.z); l.z = f2bfu(v.z - bfu2f(h.z));
    h.w = f2bfu(v.w); l.w = f2bfu(v.w - bfu2f(h.w));
    ((ushort4*)Fhi)[i4] = h;
    ((ushort4*)Flo)[i4] = l;
}

// ---------- embed [D,K] -> EhiT/EloT bf16 [K,D] + ET fp32 [K,D]
//            + enorm (fused, atomic-accumulated) + sum(cs_in) ----------
__global__ __launch_bounds__(256)
void conv_E(const float* __restrict__ E, const float* __restrict__ cs_in,
            unsigned short* __restrict__ EhiT, unsigned short* __restrict__ EloT,
            float* __restrict__ ET, float* __restrict__ enorm,
            float* __restrict__ nsum) {
    __shared__ float tile[64][65];
    int tid = threadIdx.x;
    int k0 = blockIdx.x * 64, d0 = blockIdx.y * 64;

    // sum(cs_in) partial: 128 k-blocks (y==0), one wave, one atomic each
    if (blockIdx.y == 0 && tid < 64) {
        float s = cs_in[k0 + tid];
#pragma unroll
        for (int off = 32; off; off >>= 1) s += __shfl_down(s, off);
        if (tid == 0) atomicAdd(nsum, s);
    }

#pragma unroll
    for (int it = 0; it < 16; ++it) {
        int idx = it * 256 + tid;
        int dr = idx >> 6, kc = idx & 63;
        tile[kc][dr] = E[(d0 + dr) * K + k0 + kc];
    }
    __syncthreads();
#pragma unroll
    for (int it = 0; it < 16; ++it) {
        int idx = it * 256 + tid;
        int kr = idx >> 6, dc = idx & 63;  // wave w handles row it*4+w, lanes = dc
        float v = tile[kr][dc];
        unsigned short h = f2bfu(v);
        int o = (k0 + kr) * D + d0 + dc;
        EhiT[o] = h;
        EloT[o] = f2bfu(v - bfu2f(h));
        ET[o] = v;
        // enorm partial: wave's 64 lanes hold row kr's 64 d-values of this d-block
        float ss = v * v;
#pragma unroll
        for (int off = 32; off; off >>= 1) ss += __shfl_down(ss, off);
        if ((tid & 63) == 0) atomicAdd(&enorm[k0 + kr], ss);
    }
}

// ---------- MFMA dist + fused argmin (R0 structure; acc init = -||E_k||^2/2) ----------
// acc accumulates dot - en/2, so per-ct fold is a pure argmax (dist = -2*acc,
// recovered once at the end; monotone -> argmin & tiebreak preserved).
// Validated numerically in R2/R3 benches.
__global__ __launch_bounds__(256)
void mfma_dist_argmin(const unsigned short* __restrict__ Fhi,
                      const unsigned short* __restrict__ Flo,
                      const unsigned short* __restrict__ EhiT,
                      const unsigned short* __restrict__ EloT,
                      const float* __restrict__ enorm,
                      unsigned long long* __restrict__ bestpack) {
    __shared__ unsigned short Ah[BM * BD], Al[BM * BD], Bh[BN2 * BD], Bl[BN2 * BD];

    const int tid = threadIdx.x;
    const int wave = tid >> 6;
    const int lane = tid & 63;
    const int qd = lane >> 4;
    const int ln = lane & 15;
    const int wm = (wave >> 1) * 64;
    const int wn = (wave & 1) * 64;
    const int n0 = blockIdx.x * BM;
    const int c0 = blockIdx.y * (K / CSPLIT);
    // staging: lane tid -> physical (row tid>>2, chunk tid&3); swizzled global chunk
    const int r_ = tid >> 2;
    const int s_sw = (tid & 3) ^ ((tid >> 3) & 3);
    // read swizzle: logical chunk qd of row ln lives at physical chunk qd^((ln>>1)&3)
    const int csw = (qd ^ ((ln >> 1) & 3)) * 8;

    float bestv[16];
    int besti[16];
#pragma unroll
    for (int i = 0; i < 16; ++i) { bestv[i] = -3.402823466e38f; besti[i] = 0; }

    for (int ct = 0; ct < CT_PER; ++ct) {
        const int cb = c0 + ct * BN2;

        float en[4];
#pragma unroll
        for (int ni = 0; ni < 4; ++ni) en[ni] = enorm[cb + wn + ni * 16 + ln];

        f32x4 acc[4][4];
#pragma unroll
        for (int ni = 0; ni < 4; ++ni) {
            const float e = -0.5f * en[ni];
#pragma unroll
            for (int mi = 0; mi < 4; ++mi) acc[mi][ni] = (f32x4){e, e, e, e};
        }

        for (int d0 = 0; d0 < D; d0 += BD) {
            __syncthreads();
#pragma unroll
            for (int it = 0; it < 2; ++it) {
                const int ga = (n0 + it * 64 + r_) * D + d0 + s_sw * 8;
                const int gb = (cb + it * 64 + r_) * D + d0 + s_sw * 8;
                const int lo = it * 2048 + wave * 512;
                gl_lds16(Fhi + ga, &Ah[lo]);
                gl_lds16(Flo + ga, &Al[lo]);
                gl_lds16(EhiT + gb, &Bh[lo]);
                gl_lds16(EloT + gb, &Bl[lo]);
            }
            __syncthreads();

            bf16x8 ah[4], al[4], bh[4], bl[4];
#pragma unroll
            for (int mi = 0; mi < 4; ++mi) {
                int off = (wm + mi * 16 + ln) * BD + csw;
                ah[mi] = *(const bf16x8*)&Ah[off];
                al[mi] = *(const bf16x8*)&Al[off];
            }
#pragma unroll
            for (int ni = 0; ni < 4; ++ni) {
                int off = (wn + ni * 16 + ln) * BD + csw;
                bh[ni] = *(const bf16x8*)&Bh[off];
                bl[ni] = *(const bf16x8*)&Bl[off];
            }
#pragma unroll
            for (int mi = 0; mi < 4; ++mi)
#pragma unroll
                for (int ni = 0; ni < 4; ++ni)
                    acc[mi][ni] = __builtin_amdgcn_mfma_f32_16x16x32_bf16(
                        ah[mi], bh[ni], acc[mi][ni], 0, 0, 0);
#pragma unroll
            for (int mi = 0; mi < 4; ++mi)
#pragma unroll
                for (int ni = 0; ni < 4; ++ni)
                    acc[mi][ni] = __builtin_amdgcn_mfma_f32_16x16x32_bf16(
                        ah[mi], bl[ni], acc[mi][ni], 0, 0, 0);
#pragma unroll
            for (int mi = 0; mi < 4; ++mi)
#pragma unroll
                for (int ni = 0; ni < 4; ++ni)
                    acc[mi][ni] = __builtin_amdgcn_mfma_f32_16x16x32_bf16(
                        al[mi], bh[ni], acc[mi][ni], 0, 0, 0);
        }

        // fold: pure argmax of acc (= dot - en/2) into per-row best
#pragma unroll
        for (int ni = 0; ni < 4; ++ni) {
            const int k = cb + wn + ni * 16 + ln;
#pragma unroll
            for (int mi = 0; mi < 4; ++mi) {
#pragma unroll
                for (int r = 0; r < 4; ++r) {
                    const float a = acc[mi][ni][r];
                    const int bi = mi * 4 + r;
                    if (a > bestv[bi]) { bestv[bi] = a; besti[bi] = k; }
                }
            }
        }
    }

    // cross-lane argmax per row (16 lanes of a qd-group share a row)
#pragma unroll
    for (int mi = 0; mi < 4; ++mi) {
#pragma unroll
        for (int r = 0; r < 4; ++r) {
            int bi = mi * 4 + r;
            float v = bestv[bi];
            int ix = besti[bi];
#pragma unroll
            for (int off = 1; off < 16; off <<= 1) {
                float v2 = __shfl_xor(v, off);
                int i2 = __shfl_xor(ix, off);
                if (v2 > v || (v2 == v && i2 < ix)) { v = v2; ix = i2; }
            }
            if (ln == 0) {
                int m = n0 + wm + mi * 16 + qd * 4 + r;
                const float dist = -2.0f * v;
                unsigned long long pack =
                    ((unsigned long long)enc_f32(dist) << 32) | (unsigned int)ix;
                atomicMin(&bestpack[m], pack);
            }
        }
    }
}

// ---------- gather quantize, diff partial, segment-sum scatter ----------
// R5 body; diff partial goes to diffpart[bid] (plain store) instead of a
// same-address atomicAdd tail (2048 serialized L2 RMWs removed).
#define ROWS_PER_BLOCK 16
__global__ __launch_bounds__(256)
void assign_apply(const float* __restrict__ z,   // [NTOT, D]
                  const float* __restrict__ ET,  // [K, D]
                  const unsigned long long* __restrict__ bestpack,
                  float* __restrict__ out_q, float* __restrict__ out_ind,
                  float* __restrict__ counts, float* __restrict__ esumT,
                  float* __restrict__ diffpart) {
    const int tx = threadIdx.x;  // = d
    const int rbase = blockIdx.x * ROWS_PER_BLOCK;
    float part = 0.f;
    for (int r = 0; r < ROWS_PER_BLOCK; ++r) {
        int n = rbase + r;
        unsigned long long p = bestpack[n];
        int idx = (int)(p & 0xFFFFFFFFull);
        float f = z[n * D + tx];
        float q = ET[idx * D + tx];
        out_q[n * D + tx] = q;
        float dd = q - f;
        part += dd * dd;
        atomicAdd(&esumT[idx * D + tx], f);
        if (tx == 0) {
            atomicAdd(&counts[idx], 1.0f);
            out_ind[n] = (float)idx;
        }
    }
#pragma unroll
    for (int off = 32; off; off >>= 1) part += __shfl_down(part, off);
    __shared__ float wsum[4];
    if ((tx & 63) == 0) wsum[tx >> 6] = part;
    __syncthreads();
    if (tx == 0) diffpart[blockIdx.x] = wsum[0] + wsum[1] + wsum[2] + wsum[3];
}

// ---------- embed_new (csn/nsum fused) + diff final reduce ----------
__global__ __launch_bounds__(256)
void finalize(const float* __restrict__ eavg, const float* __restrict__ esumT,
              const float* __restrict__ cs_in, const float* __restrict__ counts,
              const float* __restrict__ nsum, const float* __restrict__ diffpart,
              float* __restrict__ out_enew, float* __restrict__ out_diff) {
    const int tid = threadIdx.x;
    if (blockIdx.x == 0) {
        float p = 0.f;
#pragma unroll
        for (int j = 0; j < 8; ++j) p += diffpart[tid + 256 * j];  // 2048 partials
#pragma unroll
        for (int off = 32; off; off >>= 1) p += __shfl_down(p, off);
        __shared__ float sred[4];
        if ((tid & 63) == 0) sred[tid >> 6] = p;
        __syncthreads();
        if (tid == 0)
            *out_diff = (sred[0] + sred[1] + sred[2] + sred[3]) * (0.25f / 8388608.0f);
    }
    const int idx = blockIdx.x * 256 + tid;  // d*K + k
    // n = sum(csn) = 0.99*sum(cs_in) + 0.01*sum(counts); sum(counts) == NTOT exact
    const float nv = 0.99f * nsum[0] + 0.01f * 32768.0f;
    const int k = idx & (K - 1);
    const int d = idx >> 13;
    const float csn_k = 0.99f * cs_in[k] + 0.01f * counts[k];
    const float avg_new = 0.99f * eavg[idx] + 0.01f * esumT[k * D + d];
    const float cs = (csn_k + 1e-5f) / (nv + 0.08192f) * nv;
    out_enew[idx] = avg_new / cs;
}

extern "C" void kernel_launch(void* const* d_in, const int* in_sizes, int n_in,
                              void* d_out, int out_size, void* d_ws, size_t ws_size,
                              hipStream_t stream) {
    const float* z = (const float*)d_in[0];      // [32,32,32,256]
    const float* embed = (const float*)d_in[1];  // [256, 8192]
    const float* cs_in = (const float*)d_in[2];  // [8192]
    const float* eavg = (const float*)d_in[3];   // [256, 8192]

    float* out = (float*)d_out;
    float* out_q = out;                  // 8388608
    float* out_diff = out + 8388608;     // 1
    float* out_ind = out + 8388609;      // 32768
    float* out_enew = out + 8421377;     // 2097152

    char* ws = (char*)d_ws;
    unsigned long long* bestpack = (unsigned long long*)ws;   // 256 KB (0xFF)
    float* counts = (float*)(ws + 262144);                    // 32 KB (zero)
    float* nsum = (float*)(ws + 294912);                      // 256 B (zero)
    float* enorm = (float*)(ws + 295168);                     // 32 KB (zero, accumulated)
    float* esumT = (float*)(ws + 327936);                     // 8 MB  (zero) [K,D]
    unsigned short* Fhi = (unsigned short*)(ws + 8716544);    // 16 MB
    unsigned short* Flo = (unsigned short*)(ws + 25493760);   // 16 MB
    unsigned short* EhiT = (unsigned short*)(ws + 42270976);  // 4 MB
    unsigned short* EloT = (unsigned short*)(ws + 46465280);  // 4 MB
    float* ET = (float*)(ws + 50659584);                      // 8 MB -> end 59048192
    // diffpart ALIASES the head of Fhi: Fhi is dead once mfma_dist_argmin
    // completes, and assign_apply (the writer) is stream-ordered after it.
    // Keeps workspace high-water mark at the R5-proven 59048192 bytes.
    float* diffpart = (float*)(ws + 8716544);                 // 8 KB (written, no init)

    hipMemsetAsync(bestpack, 0xFF, 262144, stream);
    hipMemsetAsync(ws + 262144, 0, 8454400, stream);  // counts+nsum+enorm+esumT

    conv_F<<<NTOT * D / 4 / 256, 256, 0, stream>>>(z, Fhi, Flo);
    conv_E<<<dim3(K / 64, D / 64), 256, 0, stream>>>(embed, cs_in, EhiT, EloT, ET,
                                                     enorm, nsum);
    mfma_dist_argmin<<<dim3(NTOT / BM, CSPLIT), 256, 0, stream>>>(Fhi, Flo, EhiT, EloT,
                                                                  enorm, bestpack);
    assign_apply<<<NTOT / ROWS_PER_BLOCK, 256, 0, stream>>>(z, ET, bestpack, out_q,
                                                            out_ind, counts, esumT,
                                                            diffpart);
    finalize<<<(D * K) / 256, 256, 0, stream>>>(eavg, esumT, cs_in, counts, nsum,
                                                diffpart, out_enew, out_diff);
}

// Round 8
// 584.628 us; speedup vs baseline: 1.4129x; 1.0111x over previous
//
#include <hip/hip_runtime.h>
#include <hip/hip_bf16.h>

#define D 256
#define K 8192
#define NTOT 32768
#define BM 128
#define BN2 128
#define BD 32
#define CSPLIT 4
#define CT_PER (K / CSPLIT / BN2)  // 16 code-tiles per block

typedef __bf16 bf16x8 __attribute__((ext_vector_type(8)));
typedef float f32x4 __attribute__((ext_vector_type(4)));

__device__ __forceinline__ void gl_lds16(const void* g, void* l) {
    __builtin_amdgcn_global_load_lds(
        (__attribute__((address_space(1))) void*)(g),
        (__attribute__((address_space(3))) void*)(l), 16, 0, 0);
}

__device__ __forceinline__ unsigned int enc_f32(float f) {
    unsigned int u = __float_as_uint(f);
    return (u & 0x80000000u) ? ~u : (u | 0x80000000u);
}

__device__ __forceinline__ unsigned short f2bfu(float x) {
    __hip_bfloat16 h = __float2bfloat16(x);
    return __builtin_bit_cast(unsigned short, h);
}
__device__ __forceinline__ float bfu2f(unsigned short u) {
    return __bfloat162float(__builtin_bit_cast(__hip_bfloat16, u));
}

// ---------- z -> Fhi/Flo bf16 [NTOT, D] ----------
__global__ __launch_bounds__(256)
void conv_F(const float* __restrict__ z, unsigned short* __restrict__ Fhi,
            unsigned short* __restrict__ Flo) {
    int i4 = blockIdx.x * 256 + threadIdx.x;
    float4 v = ((const float4*)z)[i4];
    ushort4 h, l;
    h.x = f2bfu(v.x); l.x = f2bfu(v.x - bfu2f(h.x));
    h.y = f2bfu(v.y); l.y = f2bfu(v.y - bfu2f(h.y));
    h.z = f2bfu(v.z); l.z = f2bfu(v.z - bfu2f(h.z));
    h.w = f2bfu(v.w); l.w = f2bfu(v.w - bfu2f(h.w));
    ((ushort4*)Fhi)[i4] = h;
    ((ushort4*)Flo)[i4] = l;
}

// ---------- embed [D,K] -> EhiT/EloT bf16 [K,D] + ET fp32 [K,D]
//            + enorm (fused, atomic-accumulated) + sum(cs_in) ----------
__global__ __launch_bounds__(256)
void conv_E(const float* __restrict__ E, const float* __restrict__ cs_in,
            unsigned short* __restrict__ EhiT, unsigned short* __restrict__ EloT,
            float* __restrict__ ET, float* __restrict__ enorm,
            float* __restrict__ nsum) {
    __shared__ float tile[64][65];
    int tid = threadIdx.x;
    int k0 = blockIdx.x * 64, d0 = blockIdx.y * 64;

    // sum(cs_in) partial: 128 k-blocks (y==0), one wave, one atomic each
    if (blockIdx.y == 0 && tid < 64) {
        float s = cs_in[k0 + tid];
#pragma unroll
        for (int off = 32; off; off >>= 1) s += __shfl_down(s, off);
        if (tid == 0) atomicAdd(nsum, s);
    }

#pragma unroll
    for (int it = 0; it < 16; ++it) {
        int idx = it * 256 + tid;
        int dr = idx >> 6, kc = idx & 63;
        tile[kc][dr] = E[(d0 + dr) * K + k0 + kc];
    }
    __syncthreads();
#pragma unroll
    for (int it = 0; it < 16; ++it) {
        int idx = it * 256 + tid;
        int kr = idx >> 6, dc = idx & 63;  // wave w handles row it*4+w, lanes = dc
        float v = tile[kr][dc];
        unsigned short h = f2bfu(v);
        int o = (k0 + kr) * D + d0 + dc;
        EhiT[o] = h;
        EloT[o] = f2bfu(v - bfu2f(h));
        ET[o] = v;
        // enorm partial: wave's 64 lanes hold row kr's 64 d-values of this d-block
        float ss = v * v;
#pragma unroll
        for (int off = 32; off; off >>= 1) ss += __shfl_down(ss, off);
        if ((tid & 63) == 0) atomicAdd(&enorm[k0 + kr], ss);
    }
}

// ---------- MFMA dist + fused argmin (EXACT R0/R5 body: 431 us proven) ----------
// zero acc-init (dependency-free accvgpr_write); en loaded at FOLD time where
// it overlaps the MFMA chain (R7's head-of-tile en-init cost +29 us — reverted).
__global__ __launch_bounds__(256)
void mfma_dist_argmin(const unsigned short* __restrict__ Fhi,
                      const unsigned short* __restrict__ Flo,
                      const unsigned short* __restrict__ EhiT,
                      const unsigned short* __restrict__ EloT,
                      const float* __restrict__ enorm,
                      unsigned long long* __restrict__ bestpack) {
    __shared__ unsigned short Ah[BM * BD], Al[BM * BD], Bh[BN2 * BD], Bl[BN2 * BD];

    const int tid = threadIdx.x;
    const int wave = tid >> 6;
    const int lane = tid & 63;
    const int qd = lane >> 4;
    const int ln = lane & 15;
    const int wm = (wave >> 1) * 64;
    const int wn = (wave & 1) * 64;
    const int n0 = blockIdx.x * BM;
    const int c0 = blockIdx.y * (K / CSPLIT);
    // staging: lane tid -> physical (row tid>>2, chunk tid&3); swizzled global chunk
    const int r_ = tid >> 2;
    const int s_sw = (tid & 3) ^ ((tid >> 3) & 3);
    // read swizzle: logical chunk qd of row ln lives at physical chunk qd^((ln>>1)&3)
    const int csw = (qd ^ ((ln >> 1) & 3)) * 8;

    float bestv[16];
    int besti[16];
#pragma unroll
    for (int i = 0; i < 16; ++i) { bestv[i] = 3.402823466e38f; besti[i] = 0; }

    for (int ct = 0; ct < CT_PER; ++ct) {
        const int cb = c0 + ct * BN2;
        f32x4 acc[4][4];
#pragma unroll
        for (int mi = 0; mi < 4; ++mi)
#pragma unroll
            for (int ni = 0; ni < 4; ++ni) acc[mi][ni] = (f32x4){0.f, 0.f, 0.f, 0.f};

        for (int d0 = 0; d0 < D; d0 += BD) {
            __syncthreads();
#pragma unroll
            for (int it = 0; it < 2; ++it) {
                const int ga = (n0 + it * 64 + r_) * D + d0 + s_sw * 8;
                const int gb = (cb + it * 64 + r_) * D + d0 + s_sw * 8;
                const int lo = it * 2048 + wave * 512;
                gl_lds16(Fhi + ga, &Ah[lo]);
                gl_lds16(Flo + ga, &Al[lo]);
                gl_lds16(EhiT + gb, &Bh[lo]);
                gl_lds16(EloT + gb, &Bl[lo]);
            }
            __syncthreads();

            bf16x8 ah[4], al[4], bh[4], bl[4];
#pragma unroll
            for (int mi = 0; mi < 4; ++mi) {
                int off = (wm + mi * 16 + ln) * BD + csw;
                ah[mi] = *(const bf16x8*)&Ah[off];
                al[mi] = *(const bf16x8*)&Al[off];
            }
#pragma unroll
            for (int ni = 0; ni < 4; ++ni) {
                int off = (wn + ni * 16 + ln) * BD + csw;
                bh[ni] = *(const bf16x8*)&Bh[off];
                bl[ni] = *(const bf16x8*)&Bl[off];
            }
#pragma unroll
            for (int mi = 0; mi < 4; ++mi)
#pragma unroll
                for (int ni = 0; ni < 4; ++ni)
                    acc[mi][ni] = __builtin_amdgcn_mfma_f32_16x16x32_bf16(
                        ah[mi], bh[ni], acc[mi][ni], 0, 0, 0);
#pragma unroll
            for (int mi = 0; mi < 4; ++mi)
#pragma unroll
                for (int ni = 0; ni < 4; ++ni)
                    acc[mi][ni] = __builtin_amdgcn_mfma_f32_16x16x32_bf16(
                        ah[mi], bl[ni], acc[mi][ni], 0, 0, 0);
#pragma unroll
            for (int mi = 0; mi < 4; ++mi)
#pragma unroll
                for (int ni = 0; ni < 4; ++ni)
                    acc[mi][ni] = __builtin_amdgcn_mfma_f32_16x16x32_bf16(
                        al[mi], bh[ni], acc[mi][ni], 0, 0, 0);
        }

        float en[4];
#pragma unroll
        for (int ni = 0; ni < 4; ++ni) en[ni] = enorm[cb + wn + ni * 16 + ln];
#pragma unroll
        for (int ni = 0; ni < 4; ++ni) {
            int k = cb + wn + ni * 16 + ln;
#pragma unroll
            for (int mi = 0; mi < 4; ++mi) {
                f32x4 a = acc[mi][ni];
#pragma unroll
                for (int r = 0; r < 4; ++r) {
                    float dist = en[ni] - 2.0f * a[r];
                    int bi = mi * 4 + r;
                    if (dist < bestv[bi]) { bestv[bi] = dist; besti[bi] = k; }
                }
            }
        }
    }

#pragma unroll
    for (int mi = 0; mi < 4; ++mi) {
#pragma unroll
        for (int r = 0; r < 4; ++r) {
            int bi = mi * 4 + r;
            float v = bestv[bi];
            int ix = besti[bi];
#pragma unroll
            for (int off = 1; off < 16; off <<= 1) {
                float v2 = __shfl_xor(v, off);
                int i2 = __shfl_xor(ix, off);
                if (v2 < v || (v2 == v && i2 < ix)) { v = v2; ix = i2; }
            }
            if (ln == 0) {
                int m = n0 + wm + mi * 16 + qd * 4 + r;
                unsigned long long pack =
                    ((unsigned long long)enc_f32(v) << 32) | (unsigned int)ix;
                atomicMin(&bestpack[m], pack);
            }
        }
    }
}

// ---------- gather quantize, diff partial, segment-sum scatter ----------
#define ROWS_PER_BLOCK 16
__global__ __launch_bounds__(256)
void assign_apply(const float* __restrict__ z,   // [NTOT, D]
                  const float* __restrict__ ET,  // [K, D]
                  const unsigned long long* __restrict__ bestpack,
                  float* __restrict__ out_q, float* __restrict__ out_ind,
                  float* __restrict__ counts, float* __restrict__ esumT,
                  float* __restrict__ diffpart) {
    const int tx = threadIdx.x;  // = d
    const int rbase = blockIdx.x * ROWS_PER_BLOCK;
    float part = 0.f;
    for (int r = 0; r < ROWS_PER_BLOCK; ++r) {
        int n = rbase + r;
        unsigned long long p = bestpack[n];
        int idx = (int)(p & 0xFFFFFFFFull);
        float f = z[n * D + tx];
        float q = ET[idx * D + tx];
        out_q[n * D + tx] = q;
        float dd = q - f;
        part += dd * dd;
        atomicAdd(&esumT[idx * D + tx], f);
        if (tx == 0) {
            atomicAdd(&counts[idx], 1.0f);
            out_ind[n] = (float)idx;
        }
    }
#pragma unroll
    for (int off = 32; off; off >>= 1) part += __shfl_down(part, off);
    __shared__ float wsum[4];
    if ((tx & 63) == 0) wsum[tx >> 6] = part;
    __syncthreads();
    if (tx == 0) diffpart[blockIdx.x] = wsum[0] + wsum[1] + wsum[2] + wsum[3];
}

// ---------- embed_new (csn/nsum fused) + diff final reduce ----------
__global__ __launch_bounds__(256)
void finalize(const float* __restrict__ eavg, const float* __restrict__ esumT,
              const float* __restrict__ cs_in, const float* __restrict__ counts,
              const float* __restrict__ nsum, const float* __restrict__ diffpart,
              float* __restrict__ out_enew, float* __restrict__ out_diff) {
    const int tid = threadIdx.x;
    if (blockIdx.x == 0) {
        float p = 0.f;
#pragma unroll
        for (int j = 0; j < 8; ++j) p += diffpart[tid + 256 * j];  // 2048 partials
#pragma unroll
        for (int off = 32; off; off >>= 1) p += __shfl_down(p, off);
        __shared__ float sred[4];
        if ((tid & 63) == 0) sred[tid >> 6] = p;
        __syncthreads();
        if (tid == 0)
            *out_diff = (sred[0] + sred[1] + sred[2] + sred[3]) * (0.25f / 8388608.0f);
    }
    const int idx = blockIdx.x * 256 + tid;  // d*K + k
    // n = sum(csn) = 0.99*sum(cs_in) + 0.01*sum(counts); sum(counts) == NTOT exact
    const float nv = 0.99f * nsum[0] + 0.01f * 32768.0f;
    const int k = idx & (K - 1);
    const int d = idx >> 13;
    const float csn_k = 0.99f * cs_in[k] + 0.01f * counts[k];
    const float avg_new = 0.99f * eavg[idx] + 0.01f * esumT[k * D + d];
    const float cs = (csn_k + 1e-5f) / (nv + 0.08192f) * nv;
    out_enew[idx] = avg_new / cs;
}

extern "C" void kernel_launch(void* const* d_in, const int* in_sizes, int n_in,
                              void* d_out, int out_size, void* d_ws, size_t ws_size,
                              hipStream_t stream) {
    const float* z = (const float*)d_in[0];      // [32,32,32,256]
    const float* embed = (const float*)d_in[1];  // [256, 8192]
    const float* cs_in = (const float*)d_in[2];  // [8192]
    const float* eavg = (const float*)d_in[3];   // [256, 8192]

    float* out = (float*)d_out;
    float* out_q = out;                  // 8388608
    float* out_diff = out + 8388608;     // 1
    float* out_ind = out + 8388609;      // 32768
    float* out_enew = out + 8421377;     // 2097152

    char* ws = (char*)d_ws;
    unsigned long long* bestpack = (unsigned long long*)ws;   // 256 KB (0xFF)
    float* counts = (float*)(ws + 262144);                    // 32 KB (zero)
    float* nsum = (float*)(ws + 294912);                      // 256 B (zero)
    float* enorm = (float*)(ws + 295168);                     // 32 KB (zero, accumulated)
    float* esumT = (float*)(ws + 327936);                     // 8 MB  (zero) [K,D]
    unsigned short* Fhi = (unsigned short*)(ws + 8716544);    // 16 MB
    unsigned short* Flo = (unsigned short*)(ws + 25493760);   // 16 MB
    unsigned short* EhiT = (unsigned short*)(ws + 42270976);  // 4 MB
    unsigned short* EloT = (unsigned short*)(ws + 46465280);  // 4 MB
    float* ET = (float*)(ws + 50659584);                      // 8 MB -> end 59048192
    // diffpart ALIASES the head of Fhi: Fhi is dead once mfma_dist_argmin
    // completes, and assign_apply (the writer) is stream-ordered after it.
    float* diffpart = (float*)(ws + 8716544);                 // 8 KB (written, no init)

    hipMemsetAsync(bestpack, 0xFF, 262144, stream);
    hipMemsetAsync(ws + 262144, 0, 8454400, stream);  // counts+nsum+enorm+esumT

    conv_F<<<NTOT * D / 4 / 256, 256, 0, stream>>>(z, Fhi, Flo);
    conv_E<<<dim3(K / 64, D / 64), 256, 0, stream>>>(embed, cs_in, EhiT, EloT, ET,
                                                     enorm, nsum);
    mfma_dist_argmin<<<dim3(NTOT / BM, CSPLIT), 256, 0, stream>>>(Fhi, Flo, EhiT, EloT,
                                                                  enorm, bestpack);
    assign_apply<<<NTOT / ROWS_PER_BLOCK, 256, 0, stream>>>(z, ET, bestpack, out_q,
                                                            out_ind, counts, esumT,
                                                            diffpart);
    finalize<<<(D * K) / 256, 256, 0, stream>>>(eavg, esumT, cs_in, counts, nsum,
                                                diffpart, out_enew, out_diff);
}